// Round 1
// baseline (56.147 us; speedup 1.0000x reference)
//
#include <hip/hip_runtime.h>

// Problem: B=64, T=14, planes=4, H=W=96. Use only t=0 slice.
// Demosaic -> [64,3,192,192], bilinear resize -> [64,3,384,384] f32.
constexpr int Hh = 96, Wh = 96;            // Bayer plane dims
constexpr int PLANE = Hh * Wh;             // 9216
constexpr int BSTRIDE = 14 * 4 * PLANE;    // batch stride in frames_batch (T=14)
constexpr int DN = 192;                    // demosaiced dims
constexpr int ON = 384;                    // output dims

// R plane at (even row, even col). Clamped averaging == conv/den renorm (diagonal kernel).
__device__ __forceinline__ float demosR(const float* __restrict__ P, int r, int c) {
  const int hr = r >> 1, hc = c >> 1, pr = r & 1, pc = c & 1;
  const int hr1 = (hr < Hh - 1) ? hr + 1 : hr;
  const int hc1 = (hc < Wh - 1) ? hc + 1 : hc;
  const float* row0 = P + hr * Wh;
  const float* row1 = P + hr1 * Wh;
  if (!pr) {
    if (!pc) return row0[hc];
    return 0.5f * (row0[hc] + row0[hc1]);
  }
  if (!pc) return 0.5f * (row0[hc] + row1[hc]);
  return 0.25f * (row0[hc] + row0[hc1] + row1[hc] + row1[hc1]);
}

// B plane at (odd row, odd col).
__device__ __forceinline__ float demosB(const float* __restrict__ P, int r, int c) {
  const int hr = r >> 1, hc = c >> 1, pr = r & 1, pc = c & 1;
  const int hr0 = (hr > 0) ? hr - 1 : 0;
  const int hc0 = (hc > 0) ? hc - 1 : 0;
  const float* rowm = P + hr0 * Wh;
  const float* row  = P + hr * Wh;
  if (pr) {
    if (pc) return row[hc];
    return 0.5f * (row[hc0] + row[hc]);
  }
  if (pc) return 0.5f * (rowm[hc] + row[hc]);
  return 0.25f * (rowm[hc0] + rowm[hc] + row[hc0] + row[hc]);
}

// G: G1 at (even,odd), G2 at (odd,even). Cross kernel -> explicit arm counting at borders.
__device__ __forceinline__ float demosG(const float* __restrict__ G1,
                                        const float* __restrict__ G2, int r, int c) {
  const int hr = r >> 1, hc = c >> 1, pr = r & 1, pc = c & 1;
  if (pr != pc) return pr ? G2[hr * Wh + hc] : G1[hr * Wh + hc];
  if (!pr) {  // (even,even): arms left G1[hr][hc-1], right G1[hr][hc], up G2[hr-1][hc], down G2[hr][hc]
    float s = G1[hr * Wh + hc] + G2[hr * Wh + hc];
    float n = 2.0f;
    if (hc > 0) { s += G1[hr * Wh + hc - 1]; n += 1.0f; }
    if (hr > 0) { s += G2[(hr - 1) * Wh + hc]; n += 1.0f; }
    return s / n;
  }
  // (odd,odd): up G1[hr][hc], down G1[hr+1][hc], left G2[hr][hc], right G2[hr][hc+1]
  float s = G1[hr * Wh + hc] + G2[hr * Wh + hc];
  float n = 2.0f;
  if (hr < Hh - 1) { s += G1[(hr + 1) * Wh + hc]; n += 1.0f; }
  if (hc < Wh - 1) { s += G2[hr * Wh + hc + 1]; n += 1.0f; }
  return s / n;
}

// Each thread: one channel, output rows {2k, 2k+1}, cols {4q..4q+3}.
// Needs demosaic D at rows {k-1,k,k+1} x cols {2q-1..2q+2} (clamped).
__global__ __launch_bounds__(256) void fused_demosaic_resize(
    const float* __restrict__ in, float* __restrict__ out) {
  const int idx = blockIdx.x * 256 + threadIdx.x;
  const int q = idx % (ON / 4);
  int t = idx / (ON / 4);
  const int k = t % (ON / 2);
  t /= (ON / 2);
  const int c = t % 3;
  const int b = t / 3;

  const float* base = in + (size_t)b * BSTRIDE;

  const int rr[3] = { (k > 0) ? k - 1 : 0, k, (k < DN - 1) ? k + 1 : DN - 1 };
  const int cc[4] = { (q > 0) ? 2 * q - 1 : 0, 2 * q, 2 * q + 1,
                      (q < ON / 4 - 1) ? 2 * q + 2 : DN - 1 };

  float D[3][4];
  if (c == 0) {
    const float* P = base;  // R plane
    #pragma unroll
    for (int i = 0; i < 3; ++i)
      #pragma unroll
      for (int j = 0; j < 4; ++j) D[i][j] = demosR(P, rr[i], cc[j]);
  } else if (c == 1) {
    const float* G1 = base + PLANE;
    const float* G2 = base + 2 * PLANE;
    #pragma unroll
    for (int i = 0; i < 3; ++i)
      #pragma unroll
      for (int j = 0; j < 4; ++j) D[i][j] = demosG(G1, G2, rr[i], cc[j]);
  } else {
    const float* P = base + 3 * PLANE;  // B plane
    #pragma unroll
    for (int i = 0; i < 3; ++i)
      #pragma unroll
      for (int j = 0; j < 4; ++j) D[i][j] = demosB(P, rr[i], cc[j]);
  }

  // horizontal bilinear blends: out cols 4q..4q+3 from D cols (local 0..3)
  float h[3][4];
  #pragma unroll
  for (int i = 0; i < 3; ++i) {
    h[i][0] = 0.25f * D[i][0] + 0.75f * D[i][1];
    h[i][1] = 0.75f * D[i][1] + 0.25f * D[i][2];
    h[i][2] = 0.25f * D[i][1] + 0.75f * D[i][2];
    h[i][3] = 0.75f * D[i][2] + 0.25f * D[i][3];
  }

  // vertical blends: row 2k uses (k-1,k) w=(.25,.75); row 2k+1 uses (k,k+1) w=(.75,.25)
  float4 ra, rb;
  ra.x = 0.25f * h[0][0] + 0.75f * h[1][0];
  ra.y = 0.25f * h[0][1] + 0.75f * h[1][1];
  ra.z = 0.25f * h[0][2] + 0.75f * h[1][2];
  ra.w = 0.25f * h[0][3] + 0.75f * h[1][3];
  rb.x = 0.75f * h[1][0] + 0.25f * h[2][0];
  rb.y = 0.75f * h[1][1] + 0.25f * h[2][1];
  rb.z = 0.75f * h[1][2] + 0.25f * h[2][2];
  rb.w = 0.75f * h[1][3] + 0.25f * h[2][3];

  float* op = out + ((size_t)(b * 3 + c) * ON + 2 * k) * ON + 4 * q;
  *reinterpret_cast<float4*>(op) = ra;
  *reinterpret_cast<float4*>(op + ON) = rb;
}

extern "C" void kernel_launch(void* const* d_in, const int* in_sizes, int n_in,
                              void* d_out, int out_size, void* d_ws, size_t ws_size,
                              hipStream_t stream) {
  const float* in = (const float*)d_in[0];
  float* out = (float*)d_out;
  const int total = 64 * 3 * (ON / 2) * (ON / 4);  // 3,538,944 threads
  fused_demosaic_resize<<<total / 256, 256, 0, stream>>>(in, out);
}

// Round 2
// 25.904 us; speedup vs baseline: 2.1675x; 2.1675x over previous
//
#include <hip/hip_runtime.h>

// B=64, T=14, 4 Bayer planes (RGGB), H=W=96. Only t=0 used.
// Fused: demosaic -> [64,3,192,192] -> bilinear 2x -> [64,3,384,384] f32.
constexpr int Hh = 96, Wh = 96;
constexpr int PLANE = Hh * Wh;          // 9216
constexpr int BSTRIDE = 14 * 4 * PLANE; // batch stride (T=14)
constexpr int DN = 192;                 // demosaiced dim
constexpr int ON = 384;                 // output dim
constexpr int QN = 96;                  // col-quads per row
constexpr int KTN = 48;                 // k-tiles (4 demos rows each)

__device__ __forceinline__ float rcpn(float n) {
  // n in {2,3,4}
  return (n == 2.0f) ? 0.5f : ((n == 3.0f) ? (1.0f / 3.0f) : 0.25f);
}

__device__ __forceinline__ void hblend(float D0, float D1, float D2, float D3,
                                       float* __restrict__ h) {
  h[0] = 0.25f * D0 + 0.75f * D1;
  h[1] = 0.75f * D1 + 0.25f * D2;
  h[2] = 0.25f * D1 + 0.75f * D2;
  h[3] = 0.75f * D2 + 0.25f * D3;
}

// Stream 6 demosaic rows (k0-1 .. k0+4, clamped) -> 8 output rows x 4 cols.
template <class F>
__device__ __forceinline__ void stream_rows(F&& rowf, int k0, float* __restrict__ op) {
  float h0[4], h1[4], h2[4];
  rowf((k0 > 0) ? k0 - 1 : 0, h0);
  rowf(k0, h1);
#pragma unroll
  for (int m = 0; m < 4; ++m) {
    const int k = k0 + m;
    float4 v;
    v.x = 0.25f * h0[0] + 0.75f * h1[0];
    v.y = 0.25f * h0[1] + 0.75f * h1[1];
    v.z = 0.25f * h0[2] + 0.75f * h1[2];
    v.w = 0.25f * h0[3] + 0.75f * h1[3];
    *reinterpret_cast<float4*>(op) = v;
    op += ON;
    rowf((k < DN - 1) ? k + 1 : DN - 1, h2);
    v.x = 0.75f * h1[0] + 0.25f * h2[0];
    v.y = 0.75f * h1[1] + 0.25f * h2[1];
    v.z = 0.75f * h1[2] + 0.25f * h2[2];
    v.w = 0.75f * h1[3] + 0.25f * h2[3];
    *reinterpret_cast<float4*>(op) = v;
    op += ON;
#pragma unroll
    for (int j = 0; j < 4; ++j) { h0[j] = h1[j]; h1[j] = h2[j]; }
  }
}

__global__ __launch_bounds__(256) void fused_demosaic_resize(
    const float* __restrict__ in, float* __restrict__ out) {
  const int idx = blockIdx.x * 256 + threadIdx.x;
  const int q = idx % QN;
  int t = idx / QN;
  const int kt = t % KTN; t /= KTN;
  const int ch = t % 3;          // wave-uniform (96*48 % 64 == 0)
  const int b = t / 3;
  const int k0 = kt * 4;

  const int qm = (q > 0) ? q - 1 : 0;
  const int qp = (q < Wh - 1) ? q + 1 : Wh - 1;
  const bool qlo = (q == 0), qhi = (q == Wh - 1);

  const float* base = in + (size_t)b * BSTRIDE;
  float* op = out + (size_t)(((b * 3 + ch) * ON + 2 * k0) * ON + 4 * q);

  if (ch == 0) {
    // R plane at (even,even). Clamp-duplication == conv/den renorm (diagonal kernel).
    const float* P = base;
    auto rowf = [&](int r, float* __restrict__ h) {
      const int hr = r >> 1;
      const float* r0 = P + hr * Wh;
      float a = r0[qm], bb = r0[q], c = r0[qp];
      if (r & 1) {
        const float* r1 = P + ((hr < Hh - 1) ? hr + 1 : hr) * Wh;
        a = 0.5f * (a + r1[qm]);
        bb = 0.5f * (bb + r1[q]);
        c = 0.5f * (c + r1[qp]);
      }
      hblend(0.5f * (a + bb), bb, 0.5f * (bb + c), c, h);
    };
    stream_rows(rowf, k0, op);
  } else if (ch == 2) {
    // B plane at (odd,odd).
    const float* P = base + 3 * PLANE;
    auto rowf = [&](int r, float* __restrict__ h) {
      const int hr = r >> 1;
      const float* r0 = P + hr * Wh;
      float a = r0[qm], bb = r0[q], c = r0[qp];
      if (!(r & 1)) {
        const float* rm = P + ((hr > 0) ? hr - 1 : 0) * Wh;
        a = 0.5f * (a + rm[qm]);
        bb = 0.5f * (bb + rm[q]);
        c = 0.5f * (c + rm[qp]);
      }
      hblend(a, 0.5f * (a + bb), bb, 0.5f * (bb + c), h);
    };
    stream_rows(rowf, k0, op);
  } else {
    // G: G1 at (even,odd), G2 at (odd,even). Cross kernel -> arm counting.
    const float* G1 = base + PLANE;
    const float* G2 = base + 2 * PLANE;
    const float wQm = qlo ? 0.0f : 1.0f;  // left arm at hc=q exists
    const float wQp = qhi ? 0.0f : 1.0f;  // right arm at hc=q exists
    auto rowf = [&](int r, float* __restrict__ h) {
      const int hr = r >> 1;
      float D0, D1, D2, D3;
      if (r & 1) {
        // odd row: G2 native at even cols; cross-odd at odd cols.
        const float* g1 = G1 + hr * Wh;
        const float* g1p = G1 + ((hr < Hh - 1) ? hr + 1 : hr) * Wh;
        const float* g2 = G2 + hr * Wh;
        const float wD = (hr < Hh - 1) ? 1.0f : 0.0f;
        const float g2qm = g2[qm], g2q = g2[q], g2qp = g2[qp];
        // hc=q-1: up g1[qm], down g1p[qm] (wD), left g2[qm], right g2[q] (always)
        D0 = (g1[qm] + g2qm + g2q + wD * g1p[qm]) * rcpn(3.0f + wD);
        D1 = g2q;
        // hc=q: up g1[q], down g1p[q] (wD), left g2[q], right g2[qp] (wQp)
        D2 = (g1[q] + g2q + wD * g1p[q] + wQp * g2qp) * rcpn(2.0f + wD + wQp);
        D3 = g2qp;
      } else {
        // even row: G1 native at odd cols; cross-even at even cols.
        const float* g1 = G1 + hr * Wh;
        const float* g2 = G2 + hr * Wh;
        const float* g2m = G2 + ((hr > 0) ? hr - 1 : 0) * Wh;
        const float wU = (hr > 0) ? 1.0f : 0.0f;
        const float g1qm = g1[qm], g1q = g1[q], g1qp = g1[qp];
        D0 = g1qm;
        // hc=q: right g1q, left g1qm (wQm), down g2[q], up g2m[q] (wU)
        D1 = (g1q + g2[q] + wQm * g1qm + wU * g2m[q]) * rcpn(2.0f + wQm + wU);
        D2 = g1q;
        // hc=qp: right g1qp, left g1q (valid for q<95), down g2[qp], up g2m[qp] (wU)
        D3 = (g1qp + g2[qp] + g1q + wU * g2m[qp]) * rcpn(3.0f + wU);
      }
      if (qlo) D0 = D1;  // col -1 clamps onto col 0
      if (qhi) D3 = D2;  // col 192 clamps onto col 191
      hblend(D0, D1, D2, D3, h);
    };
    stream_rows(rowf, k0, op);
  }
}

extern "C" void kernel_launch(void* const* d_in, const int* in_sizes, int n_in,
                              void* d_out, int out_size, void* d_ws, size_t ws_size,
                              hipStream_t stream) {
  const float* in = (const float*)d_in[0];
  float* out = (float*)d_out;
  const int total = 64 * 3 * KTN * QN;  // 884,736 threads, 3456 blocks
  fused_demosaic_resize<<<total / 256, 256, 0, stream>>>(in, out);
}

// Round 4
// 25.078 us; speedup vs baseline: 2.2389x; 1.0329x over previous
//
#include <hip/hip_runtime.h>

// B=64, T=14, 4 Bayer planes (RGGB), H=W=96. Only t=0 used.
// Fused: demosaic -> [64,3,192,192] -> bilinear 2x -> [64,3,384,384] f32.
constexpr int Hh = 96, Wh = 96;
constexpr int PLANE = Hh * Wh;          // 9216
constexpr int BSTRIDE = 14 * 4 * PLANE; // batch stride (T=14)
constexpr int ON = 384;                 // output dim
constexpr int QN = 96;                  // col-quads per row
constexpr int KTN = 48;                 // k-tiles (4 demosaic rows each)

typedef float f32x4 __attribute__((ext_vector_type(4)));

__device__ __forceinline__ float rcpn(float n) {
  // n in {2,3,4}
  return (n == 2.0f) ? 0.5f : ((n == 3.0f) ? (1.0f / 3.0f) : 0.25f);
}

__device__ __forceinline__ void hblend(float D0, float D1, float D2, float D3,
                                       float* __restrict__ h) {
  h[0] = 0.25f * D0 + 0.75f * D1;
  h[1] = 0.75f * D1 + 0.25f * D2;
  h[2] = 0.25f * D1 + 0.75f * D2;
  h[3] = 0.75f * D2 + 0.25f * D3;
}

// Each thread: one channel, demosaic rows k0-1..k0+4 (k0=4*kt) -> 8 output
// rows x 4 cols. All input loads issued upfront (dedup'd), branch-free compute
// (row parities are compile-time constant), nontemporal float4 stores.
__global__ __launch_bounds__(256) void fused_demosaic_resize(
    const float* __restrict__ in, float* __restrict__ out) {
  const int idx = blockIdx.x * 256 + threadIdx.x;
  const int q = idx % QN;
  int t = idx / QN;
  const int kt = t % KTN; t /= KTN;
  const int ch = t % 3;          // wave-uniform
  const int b = t / 3;

  const int qm = (q > 0) ? q - 1 : 0;
  const int qp = (q < Wh - 1) ? q + 1 : Wh - 1;
  const bool qlo = (q == 0), qhi = (q == Wh - 1);

  // plane rows needed for demosaic rows 4kt-1 .. 4kt+4 (clamped)
  const int pr[4] = { (kt > 0) ? 2 * kt - 1 : 0, 2 * kt, 2 * kt + 1,
                      (kt < KTN - 1) ? 2 * kt + 2 : Hh - 1 };

  const float* base = in + (size_t)b * BSTRIDE;

  float h[6][4];  // h[i] = horizontal blends of demosaic row k0-1+i

  if (ch == 1) {
    // G: G1 at (even,odd), G2 at (odd,even). Cross kernel -> arm counting.
    const float* G1 = base + PLANE;
    const float* G2 = base + 2 * PLANE;
    float g1v[4][3], g2v[4][3];
#pragma unroll
    for (int i = 0; i < 4; ++i) {
      const float* a = G1 + pr[i] * Wh;
      const float* c = G2 + pr[i] * Wh;
      g1v[i][0] = a[qm]; g1v[i][1] = a[q]; g1v[i][2] = a[qp];
      g2v[i][0] = c[qm]; g2v[i][1] = c[q]; g2v[i][2] = c[qp];
    }
    const float wQm = qlo ? 0.0f : 1.0f;
    const float wQp = qhi ? 0.0f : 1.0f;
    // odd demosaic row r=2t+1: G2 native at even cols; cross at odd cols.
    auto godd = [&](const float* g1u, const float* g1d, const float* g2,
                    float wD, float* hh) {
      float D0 = (g1u[0] + g2[0] + g2[1] + wD * g1d[0]) * rcpn(3.0f + wD);
      float D1 = g2[1];
      float D2 = (g1u[1] + g2[1] + wD * g1d[1] + wQp * g2[2]) * rcpn(2.0f + wD + wQp);
      float D3 = g2[2];
      if (qlo) D0 = D1;
      if (qhi) D3 = D2;
      hblend(D0, D1, D2, D3, hh);
    };
    // even demosaic row r=2t: G1 native at odd cols; cross at even cols.
    auto geven = [&](const float* g1, const float* g2u, const float* g2d,
                     float wU, float* hh) {
      float D0 = g1[0];
      float D1 = (g1[1] + g2d[1] + wQm * g1[0] + wU * g2u[1]) * rcpn(2.0f + wQm + wU);
      float D2 = g1[1];
      float D3 = (g1[2] + g2d[2] + g1[1] + wU * g2u[2]) * rcpn(3.0f + wU);
      if (qlo) D0 = D1;
      if (qhi) D3 = D2;
      hblend(D0, D1, D2, D3, hh);
    };
    godd (g1v[0], g1v[1], g2v[0], 1.0f, h[0]);                         // d(4kt-1)
    geven(g1v[1], g2v[0], g2v[1], (kt > 0) ? 1.0f : 0.0f, h[1]);       // d(4kt)
    godd (g1v[1], g1v[2], g2v[1], 1.0f, h[2]);                         // d(4kt+1)
    geven(g1v[2], g2v[1], g2v[2], 1.0f, h[3]);                         // d(4kt+2)
    godd (g1v[2], g1v[3], g2v[2], (kt < KTN - 1) ? 1.0f : 0.0f, h[4]); // d(4kt+3)
    geven(g1v[3], g2v[2], g2v[3], 1.0f, h[5]);                         // d(4kt+4)
  } else {
    // R at (even,even) / B at (odd,odd): clamp-duplication == conv/den renorm.
    const float* P = (ch == 0) ? base : base + 3 * PLANE;
    float A[4][3];
#pragma unroll
    for (int i = 0; i < 4; ++i) {
      const float* r = P + pr[i] * Wh;
      A[i][0] = r[qm]; A[i][1] = r[q]; A[i][2] = r[qp];
    }
    if (ch == 0) {
      auto rrow = [&](float a, float b_, float c, float* hh) {
        hblend(0.5f * (a + b_), b_, 0.5f * (b_ + c), c, hh);
      };
      rrow(0.5f * (A[0][0] + A[1][0]), 0.5f * (A[0][1] + A[1][1]), 0.5f * (A[0][2] + A[1][2]), h[0]);
      rrow(A[1][0], A[1][1], A[1][2], h[1]);
      rrow(0.5f * (A[1][0] + A[2][0]), 0.5f * (A[1][1] + A[2][1]), 0.5f * (A[1][2] + A[2][2]), h[2]);
      rrow(A[2][0], A[2][1], A[2][2], h[3]);
      rrow(0.5f * (A[2][0] + A[3][0]), 0.5f * (A[2][1] + A[3][1]), 0.5f * (A[2][2] + A[3][2]), h[4]);
      rrow(A[3][0], A[3][1], A[3][2], h[5]);
    } else {
      auto brow = [&](float a, float b_, float c, float* hh) {
        hblend(a, 0.5f * (a + b_), b_, 0.5f * (b_ + c), hh);
      };
      brow(A[0][0], A[0][1], A[0][2], h[0]);
      brow(0.5f * (A[0][0] + A[1][0]), 0.5f * (A[0][1] + A[1][1]), 0.5f * (A[0][2] + A[1][2]), h[1]);
      brow(A[1][0], A[1][1], A[1][2], h[2]);
      brow(0.5f * (A[1][0] + A[2][0]), 0.5f * (A[1][1] + A[2][1]), 0.5f * (A[1][2] + A[2][2]), h[3]);
      brow(A[2][0], A[2][1], A[2][2], h[4]);
      brow(0.5f * (A[2][0] + A[3][0]), 0.5f * (A[2][1] + A[3][1]), 0.5f * (A[2][2] + A[3][2]), h[5]);
    }
  }

  // tile-edge overrides: required for G (structure flips at clamped rows);
  // value-neutral for R/B (clamped rows already duplicate).
#pragma unroll
  for (int j = 0; j < 4; ++j) {
    if (kt == 0)       h[0][j] = h[1][j];
    if (kt == KTN - 1) h[5][j] = h[4][j];
  }

  float* op = out + (size_t)(((b * 3 + ch) * ON + 8 * kt) * ON + 4 * q);
#pragma unroll
  for (int m = 0; m < 4; ++m) {
    f32x4 v;
    v.x = 0.25f * h[m][0] + 0.75f * h[m + 1][0];
    v.y = 0.25f * h[m][1] + 0.75f * h[m + 1][1];
    v.z = 0.25f * h[m][2] + 0.75f * h[m + 1][2];
    v.w = 0.25f * h[m][3] + 0.75f * h[m + 1][3];
    __builtin_nontemporal_store(v, reinterpret_cast<f32x4*>(op));
    op += ON;
    v.x = 0.75f * h[m + 1][0] + 0.25f * h[m + 2][0];
    v.y = 0.75f * h[m + 1][1] + 0.25f * h[m + 2][1];
    v.z = 0.75f * h[m + 1][2] + 0.25f * h[m + 2][2];
    v.w = 0.75f * h[m + 1][3] + 0.25f * h[m + 2][3];
    __builtin_nontemporal_store(v, reinterpret_cast<f32x4*>(op));
    op += ON;
  }
}

extern "C" void kernel_launch(void* const* d_in, const int* in_sizes, int n_in,
                              void* d_out, int out_size, void* d_ws, size_t ws_size,
                              hipStream_t stream) {
  const float* in = (const float*)d_in[0];
  float* out = (float*)d_out;
  const int total = 64 * 3 * KTN * QN;  // 884,736 threads, 3456 blocks
  fused_demosaic_resize<<<total / 256, 256, 0, stream>>>(in, out);
}

// Round 5
// 24.964 us; speedup vs baseline: 2.2491x; 1.0046x over previous
//
#include <hip/hip_runtime.h>

// B=64, T=14, 4 Bayer planes (RGGB), H=W=96. Only t=0 used.
// Fused: demosaic -> [64,3,192,192] -> bilinear 2x -> [64,3,384,384] f32.
constexpr int Hh = 96, Wh = 96;
constexpr int PLANE = Hh * Wh;          // 9216
constexpr int BSTRIDE = 14 * 4 * PLANE; // batch stride (T=14)
constexpr int ON = 384;                 // output dim
constexpr int QN = 96;                  // col-quads per row
constexpr int KTN = 48;                 // k-tiles (4 demosaic rows each)
constexpr int BLK_PER_IMG = KTN * QN / 256;  // 18 blocks per (b,ch)

typedef float f32x4 __attribute__((ext_vector_type(4)));

__device__ __forceinline__ float rcpn(float n) {
  // n in {2,3,4}
  return (n == 2.0f) ? 0.5f : ((n == 3.0f) ? (1.0f / 3.0f) : 0.25f);
}

__device__ __forceinline__ void hblend(float D0, float D1, float D2, float D3,
                                       float* __restrict__ h) {
  h[0] = 0.25f * D0 + 0.75f * D1;
  h[1] = 0.75f * D1 + 0.25f * D2;
  h[2] = 0.25f * D1 + 0.75f * D2;
  h[3] = 0.75f * D2 + 0.25f * D3;
}

// Each thread: one channel, demosaic rows k0-1..k0+4 (k0=4*kt) -> 8 output
// rows x 4 cols. Batched dedup'd loads, branch-free compute, nt float4 stores.
// Blocks cycle channels (blk%3) so heavy G blocks spread across all CUs.
__global__ __launch_bounds__(256, 6) void fused_demosaic_resize(
    const float* __restrict__ in, float* __restrict__ out) {
  const int blk = blockIdx.x;
  const int ch = blk % 3;                // wave-uniform (block-pure)
  const int rest = blk / 3;              // 0..1151
  const int b = rest / BLK_PER_IMG;
  const int s = rest % BLK_PER_IMG;
  const int u = s * 256 + threadIdx.x;   // 0..4607 within (b,ch)
  const int kt = u / QN;
  const int q = u % QN;

  const int qm = (q > 0) ? q - 1 : 0;
  const int qp = (q < Wh - 1) ? q + 1 : Wh - 1;
  const bool qlo = (q == 0), qhi = (q == Wh - 1);

  // plane rows needed for demosaic rows 4kt-1 .. 4kt+4 (clamped)
  const int pr[4] = { (kt > 0) ? 2 * kt - 1 : 0, 2 * kt, 2 * kt + 1,
                      (kt < KTN - 1) ? 2 * kt + 2 : Hh - 1 };

  const float* base = in + (size_t)b * BSTRIDE;

  float h[6][4];  // h[i] = horizontal blends of demosaic row 4kt-1+i

  if (ch == 1) {
    // G: G1 at (even,odd), G2 at (odd,even). Cross kernel -> arm counting.
    const float* G1 = base + PLANE;
    const float* G2 = base + 2 * PLANE;
    float g1v[4][3], g2v[4][3];
#pragma unroll
    for (int i = 0; i < 4; ++i) {
      const float* a = G1 + pr[i] * Wh;
      const float* c = G2 + pr[i] * Wh;
      g1v[i][0] = a[qm]; g1v[i][1] = a[q]; g1v[i][2] = a[qp];
      g2v[i][0] = c[qm]; g2v[i][1] = c[q]; g2v[i][2] = c[qp];
    }
    const float wQm = qlo ? 0.0f : 1.0f;
    const float wQp = qhi ? 0.0f : 1.0f;
    // odd demosaic row r=2t+1: G2 native at even cols; cross at odd cols.
    auto godd = [&](const float* g1u, const float* g1d, const float* g2,
                    float wD, float* hh) {
      float D0 = (g1u[0] + g2[0] + g2[1] + wD * g1d[0]) * rcpn(3.0f + wD);
      float D1 = g2[1];
      float D2 = (g1u[1] + g2[1] + wD * g1d[1] + wQp * g2[2]) * rcpn(2.0f + wD + wQp);
      float D3 = g2[2];
      if (qlo) D0 = D1;
      if (qhi) D3 = D2;
      hblend(D0, D1, D2, D3, hh);
    };
    // even demosaic row r=2t: G1 native at odd cols; cross at even cols.
    auto geven = [&](const float* g1, const float* g2u, const float* g2d,
                     float wU, float* hh) {
      float D0 = g1[0];
      float D1 = (g1[1] + g2d[1] + wQm * g1[0] + wU * g2u[1]) * rcpn(2.0f + wQm + wU);
      float D2 = g1[1];
      float D3 = (g1[2] + g2d[2] + g1[1] + wU * g2u[2]) * rcpn(3.0f + wU);
      if (qlo) D0 = D1;
      if (qhi) D3 = D2;
      hblend(D0, D1, D2, D3, hh);
    };
    godd (g1v[0], g1v[1], g2v[0], 1.0f, h[0]);                         // d(4kt-1)
    geven(g1v[1], g2v[0], g2v[1], (kt > 0) ? 1.0f : 0.0f, h[1]);       // d(4kt)
    godd (g1v[1], g1v[2], g2v[1], 1.0f, h[2]);                         // d(4kt+1)
    geven(g1v[2], g2v[1], g2v[2], 1.0f, h[3]);                         // d(4kt+2)
    godd (g1v[2], g1v[3], g2v[2], (kt < KTN - 1) ? 1.0f : 0.0f, h[4]); // d(4kt+3)
    geven(g1v[3], g2v[2], g2v[3], 1.0f, h[5]);                         // d(4kt+4)
  } else {
    // R at (even,even) / B at (odd,odd): clamp-duplication == conv/den renorm.
    const float* P = (ch == 0) ? base : base + 3 * PLANE;
    float A[4][3];
#pragma unroll
    for (int i = 0; i < 4; ++i) {
      const float* r = P + pr[i] * Wh;
      A[i][0] = r[qm]; A[i][1] = r[q]; A[i][2] = r[qp];
    }
    if (ch == 0) {
      auto rrow = [&](float a, float b_, float c, float* hh) {
        hblend(0.5f * (a + b_), b_, 0.5f * (b_ + c), c, hh);
      };
      rrow(0.5f * (A[0][0] + A[1][0]), 0.5f * (A[0][1] + A[1][1]), 0.5f * (A[0][2] + A[1][2]), h[0]);
      rrow(A[1][0], A[1][1], A[1][2], h[1]);
      rrow(0.5f * (A[1][0] + A[2][0]), 0.5f * (A[1][1] + A[2][1]), 0.5f * (A[1][2] + A[2][2]), h[2]);
      rrow(A[2][0], A[2][1], A[2][2], h[3]);
      rrow(0.5f * (A[2][0] + A[3][0]), 0.5f * (A[2][1] + A[3][1]), 0.5f * (A[2][2] + A[3][2]), h[4]);
      rrow(A[3][0], A[3][1], A[3][2], h[5]);
    } else {
      auto brow = [&](float a, float b_, float c, float* hh) {
        hblend(a, 0.5f * (a + b_), b_, 0.5f * (b_ + c), hh);
      };
      brow(A[0][0], A[0][1], A[0][2], h[0]);
      brow(0.5f * (A[0][0] + A[1][0]), 0.5f * (A[0][1] + A[1][1]), 0.5f * (A[0][2] + A[1][2]), h[1]);
      brow(A[1][0], A[1][1], A[1][2], h[2]);
      brow(0.5f * (A[1][0] + A[2][0]), 0.5f * (A[1][1] + A[2][1]), 0.5f * (A[1][2] + A[2][2]), h[3]);
      brow(A[2][0], A[2][1], A[2][2], h[4]);
      brow(0.5f * (A[2][0] + A[3][0]), 0.5f * (A[2][1] + A[3][1]), 0.5f * (A[2][2] + A[3][2]), h[5]);
    }
  }

  // tile-edge overrides: required for G (structure flips at clamped rows);
  // value-neutral for R/B (clamped rows already duplicate).
#pragma unroll
  for (int j = 0; j < 4; ++j) {
    if (kt == 0)       h[0][j] = h[1][j];
    if (kt == KTN - 1) h[5][j] = h[4][j];
  }

  float* op = out + (size_t)(((b * 3 + ch) * ON + 8 * kt) * ON + 4 * q);
#pragma unroll
  for (int m = 0; m < 4; ++m) {
    f32x4 v;
    v.x = 0.25f * h[m][0] + 0.75f * h[m + 1][0];
    v.y = 0.25f * h[m][1] + 0.75f * h[m + 1][1];
    v.z = 0.25f * h[m][2] + 0.75f * h[m + 1][2];
    v.w = 0.25f * h[m][3] + 0.75f * h[m + 1][3];
    __builtin_nontemporal_store(v, reinterpret_cast<f32x4*>(op));
    op += ON;
    v.x = 0.75f * h[m + 1][0] + 0.25f * h[m + 2][0];
    v.y = 0.75f * h[m + 1][1] + 0.25f * h[m + 2][1];
    v.z = 0.75f * h[m + 1][2] + 0.25f * h[m + 2][2];
    v.w = 0.75f * h[m + 1][3] + 0.25f * h[m + 2][3];
    __builtin_nontemporal_store(v, reinterpret_cast<f32x4*>(op));
    op += ON;
  }
}

extern "C" void kernel_launch(void* const* d_in, const int* in_sizes, int n_in,
                              void* d_out, int out_size, void* d_ws, size_t ws_size,
                              hipStream_t stream) {
  const float* in = (const float*)d_in[0];
  float* out = (float*)d_out;
  const int total_blocks = 64 * 3 * BLK_PER_IMG;  // 3456 blocks
  fused_demosaic_resize<<<total_blocks, 256, 0, stream>>>(in, out);
}